// Round 12
// baseline (394.133 us; speedup 1.0000x reference)
//
#include <hip/hip_runtime.h>
#include <hip/hip_bf16.h>

typedef __bf16 bf16_t;
typedef __bf16 bf16x8 __attribute__((ext_vector_type(8)));
typedef __bf16 bf16x4 __attribute__((ext_vector_type(4)));
typedef float  f32x4  __attribute__((ext_vector_type(4)));

#define D 128
#define UV_LDS   131072   // uv_kernel: 64KB weights + 8 x 8KB chunks
#define EDGE_LDS 131072   // edge_kernel: 64KB weights + 8 x 8KB chunks (32 rows/wave)

// LDS element-index swizzle: XOR multiples of 8 elems (16B) keep 8-elem groups intact.
__device__ __forceinline__ int swz(int r, int c) {
    return (r * D + c) ^ ((r & 7) << 3);
}

// 4 transposed bf16 weight slices: s<3: ws[s][n][k]=W1[(s*128+k)*128+n]; s==3: W2[k*128+n]
__global__ void prep_weights_kernel(const float* __restrict__ W1,
                                    const float* __restrict__ W2,
                                    bf16_t* __restrict__ ws) {
    int t = blockIdx.x * 256 + threadIdx.x;
    int s = t >> 14, r = t & 16383;
    int n = r >> 7, k = r & 127;
    float v = (s < 3) ? W1[(s * 128 + k) * 128 + n] : W2[k * 128 + n];
    ws[t] = (bf16_t)v;
}

// u = x·W1a + b1, v = x·W1b   (bf16 row-major outputs, gather-ready)
__global__ __launch_bounds__(512, 2)
void uv_kernel(const float* __restrict__ x, const bf16_t* __restrict__ ws,
               const float* __restrict__ b1, bf16_t* __restrict__ u,
               bf16_t* __restrict__ v, int N) {
    extern __shared__ __align__(16) bf16_t lds[];
    const int tid = threadIdx.x, lane = tid & 63, wv = tid >> 6;
    const int col0 = lane & 15, krow = lane >> 4, l31 = lane & 31, half = lane >> 5;
    const int gr = lane >> 4, gc = (lane & 15) * 8;
    const int n0 = blockIdx.x * 256 + wv * 32;
    bf16_t* Ach = lds + 32768 + wv * 4096;

    f32x4 xb[16];
#pragma unroll
    for (int j = 0; j < 16; j++) {
        int node = min(n0 + j * 2 + half, N - 1);
        xb[j] = *(const f32x4*)(x + (long long)node * D + l31 * 4);
    }
#pragma unroll
    for (int s = 0; s < 2; s++)
#pragma unroll
        for (int j = 0; j < 4; j++) {
            int row = j * 32 + (tid >> 4), slot = (tid & 15) * 8;
            bf16x8 w = *(const bf16x8*)(ws + s * 16384 + row * 128 + slot);
            *(bf16x8*)&lds[s * 16384 + swz(row, slot)] = w;
        }
    float bias1[8];
#pragma unroll
    for (int n = 0; n < 8; n++) bias1[n] = b1[n * 16 + col0];
#pragma unroll
    for (int j = 0; j < 16; j++) {
        f32x4 vv = xb[j];
        bf16x4 hv = { (bf16_t)vv.x, (bf16_t)vv.y, (bf16_t)vv.z, (bf16_t)vv.w };
        *(bf16x4*)&Ach[swz(j * 2 + half, l31 * 4)] = hv;
    }
    __syncthreads();

    f32x4 aU[2][8], aV[2][8];
#pragma unroll
    for (int m = 0; m < 2; m++)
#pragma unroll
        for (int n = 0; n < 8; n++) { aU[m][n] = (f32x4){0,0,0,0}; aV[m][n] = (f32x4){0,0,0,0}; }
#pragma unroll
    for (int kk = 0; kk < 4; kk++) {
        bf16x8 a0 = *(const bf16x8*)&Ach[swz(col0, kk*32 + krow*8)];
        bf16x8 a1 = *(const bf16x8*)&Ach[swz(16 + col0, kk*32 + krow*8)];
#pragma unroll
        for (int n = 0; n < 8; n++) {
            bf16x8 bU = *(const bf16x8*)&lds[swz(n*16 + col0, kk*32 + krow*8)];
            bf16x8 bV = *(const bf16x8*)&lds[16384 + swz(n*16 + col0, kk*32 + krow*8)];
            aU[0][n] = __builtin_amdgcn_mfma_f32_16x16x32_bf16(a0, bU, aU[0][n], 0,0,0);
            aU[1][n] = __builtin_amdgcn_mfma_f32_16x16x32_bf16(a1, bU, aU[1][n], 0,0,0);
            aV[0][n] = __builtin_amdgcn_mfma_f32_16x16x32_bf16(a0, bV, aV[0][n], 0,0,0);
            aV[1][n] = __builtin_amdgcn_mfma_f32_16x16x32_bf16(a1, bV, aV[1][n], 0,0,0);
        }
    }
#pragma unroll
    for (int m = 0; m < 2; m++)
#pragma unroll
        for (int n = 0; n < 8; n++)
#pragma unroll
            for (int ri = 0; ri < 4; ri++)
                Ach[swz(m*16 + krow*4 + ri, n*16 + col0)] = (bf16_t)(aU[m][n][ri] + bias1[n]);
#pragma unroll
    for (int j = 0; j < 8; j++) {
        int r = j * 4 + gr, node = n0 + r;
        if (node < N) *(bf16x8*)(u + (long long)node * D + gc) = *(const bf16x8*)&Ach[swz(r, gc)];
    }
#pragma unroll
    for (int m = 0; m < 2; m++)
#pragma unroll
        for (int n = 0; n < 8; n++)
#pragma unroll
            for (int ri = 0; ri < 4; ri++)
                Ach[swz(m*16 + krow*4 + ri, n*16 + col0)] = (bf16_t)(aV[m][n][ri]);
#pragma unroll
    for (int j = 0; j < 8; j++) {
        int r = j * 4 + gr, node = n0 + r;
        if (node < N) *(bf16x8*)(v + (long long)node * D + gc) = *(const bf16x8*)&Ach[swz(r, gc)];
    }
}

// Persistent: out = relu( relu(ea·W1c + u[src] + v[dst]) · W2 + b2 )
// 256 blocks x 8 waves; each wave grid-strides 32-edge groups with loop-carried prefetch.
__global__ __launch_bounds__(512, 1)
void edge_kernel(const bf16_t* __restrict__ u, const bf16_t* __restrict__ v,
                 const float* __restrict__ ea, const int* __restrict__ ei,
                 const bf16_t* __restrict__ ws, const float* __restrict__ b2,
                 float* __restrict__ out, int E) {
    extern __shared__ __align__(16) bf16_t lds[];   // [2][128][128] W1c,W2 + [8][32][128]
    const int tid = threadIdx.x, lane = tid & 63, wv = tid >> 6;
    const int col0 = lane & 15, krow = lane >> 4, l31 = lane & 31, half = lane >> 5;
    const int gr = lane >> 4, gc = (lane & 15) * 8;
    bf16_t* Ach = lds + 32768 + wv * 4096;

    const int totg = (E + 31) >> 5;       // 12500 groups of 32 edges
    const int gstr = gridDim.x * 8;       // 2048 waves
    int g = blockIdx.x * 8 + wv;

    f32x4  eaR[16];
    bf16x8 uR[8], vR[8];
    int sidxN = 0, didxN = 0;

    // ---- prologue: issue group g's loads + prefetch ei(g+1) ----
    if (g < totg) {
        int er = min(g * 32 + l31, E - 1);
        int sidx = ei[er], didx = ei[E + er];
#pragma unroll
        for (int j = 0; j < 16; j++) {
            int e = min(g * 32 + j * 2 + half, E - 1);
            eaR[j] = *(const f32x4*)(ea + (long long)e * D + l31 * 4);
        }
#pragma unroll
        for (int j = 0; j < 8; j++) { int gi = __shfl(sidx, j * 4 + gr); uR[j] = *(const bf16x8*)(u + (long long)gi * D + gc); }
#pragma unroll
        for (int j = 0; j < 8; j++) { int gi = __shfl(didx, j * 4 + gr); vR[j] = *(const bf16x8*)(v + (long long)gi * D + gc); }
        int gn = g + gstr;
        if (gn < totg) {
            int er2 = min(gn * 32 + l31, E - 1);
            sidxN = ei[er2]; didxN = ei[E + er2];
        }
    }
    // stage W1c (slice2), W2 (slice3) once per kernel
#pragma unroll
    for (int s = 0; s < 2; s++)
#pragma unroll
        for (int j = 0; j < 4; j++) {
            int row = j * 32 + (tid >> 4), slot = (tid & 15) * 8;
            bf16x8 w = *(const bf16x8*)(ws + (2 + s) * 16384 + row * 128 + slot);
            *(bf16x8*)&lds[s * 16384 + swz(row, slot)] = w;
        }
    float bias2[8];
#pragma unroll
    for (int n = 0; n < 8; n++) bias2[n] = b2[n * 16 + col0];
    __syncthreads();   // the only barrier

    while (g < totg) {
        const int gn = g + gstr;

        // ea(g) -> chunk (landed ~1 iteration ago)
#pragma unroll
        for (int j = 0; j < 16; j++) {
            f32x4 vv = eaR[j];
            bf16x4 hv = { (bf16_t)vv.x, (bf16_t)vv.y, (bf16_t)vv.z, (bf16_t)vv.w };
            *(bf16x4*)&Ach[swz(j * 2 + half, l31 * 4)] = hv;
        }
        // issue ea(g+1): in flight until next iteration's top
        if (gn < totg) {
#pragma unroll
            for (int j = 0; j < 16; j++) {
                int e = min(gn * 32 + j * 2 + half, E - 1);
                eaR[j] = *(const f32x4*)(ea + (long long)e * D + l31 * 4);
            }
        }
        // prefetch ei(g+2)
        int sidx2 = 0, didx2 = 0;
        int g2 = gn + gstr;
        if (g2 < totg) {
            int er = min(g2 * 32 + l31, E - 1);
            sidx2 = ei[er]; didx2 = ei[E + er];
        }

        // ---- A1: ea · W1c ----
        f32x4 acc[2][8];
#pragma unroll
        for (int m = 0; m < 2; m++)
#pragma unroll
            for (int n = 0; n < 8; n++) acc[m][n] = (f32x4){0,0,0,0};
#pragma unroll
        for (int kk = 0; kk < 4; kk++) {
            bf16x8 a0 = *(const bf16x8*)&Ach[swz(     col0, kk*32 + krow*8)];
            bf16x8 a1 = *(const bf16x8*)&Ach[swz(16 + col0, kk*32 + krow*8)];
#pragma unroll
            for (int n = 0; n < 8; n++) {
                bf16x8 b = *(const bf16x8*)&lds[swz(n*16 + col0, kk*32 + krow*8)];
                acc[0][n] = __builtin_amdgcn_mfma_f32_16x16x32_bf16(a0, b, acc[0][n], 0, 0, 0);
                acc[1][n] = __builtin_amdgcn_mfma_f32_16x16x32_bf16(a1, b, acc[1][n], 0, 0, 0);
            }
        }

        // p = A1 result -> chunk (C-space scalar writes; the only transpose cost)
#pragma unroll
        for (int m = 0; m < 2; m++)
#pragma unroll
            for (int n = 0; n < 8; n++)
#pragma unroll
                for (int ri = 0; ri < 4; ri++)
                    Ach[swz(m*16 + krow*4 + ri, n*16 + col0)] = (bf16_t)acc[m][n][ri];

        // h = relu(p + u + v) fused in ROW space (uR/vR already row-space registers)
#pragma unroll
        for (int j = 0; j < 8; j++) {
            bf16x8 p8 = *(const bf16x8*)&Ach[swz(j * 4 + gr, gc)];
            bf16x8 su = uR[j], sv = vR[j], h8;
#pragma unroll
            for (int t = 0; t < 8; t++)
                h8[t] = (bf16_t)fmaxf((float)p8[t] + (float)su[t] + (float)sv[t], 0.f);
            *(bf16x8*)&Ach[swz(j * 4 + gr, gc)] = h8;
        }

        // issue u/v(g+1) gathers (uR/vR now free; consumed next iteration)
        if (gn < totg) {
#pragma unroll
            for (int j = 0; j < 8; j++) { int gi = __shfl(sidxN, j * 4 + gr); uR[j] = *(const bf16x8*)(u + (long long)gi * D + gc); }
#pragma unroll
            for (int j = 0; j < 8; j++) { int gi = __shfl(didxN, j * 4 + gr); vR[j] = *(const bf16x8*)(v + (long long)gi * D + gc); }
        }

        // ---- A2: h · W2 ----
#pragma unroll
        for (int m = 0; m < 2; m++)
#pragma unroll
            for (int n = 0; n < 8; n++) acc[m][n] = (f32x4){0,0,0,0};
#pragma unroll
        for (int kk = 0; kk < 4; kk++) {
            bf16x8 a0 = *(const bf16x8*)&Ach[swz(     col0, kk*32 + krow*8)];
            bf16x8 a1 = *(const bf16x8*)&Ach[swz(16 + col0, kk*32 + krow*8)];
#pragma unroll
            for (int n = 0; n < 8; n++) {
                bf16x8 b = *(const bf16x8*)&lds[16384 + swz(n*16 + col0, kk*32 + krow*8)];
                acc[0][n] = __builtin_amdgcn_mfma_f32_16x16x32_bf16(a0, b, acc[0][n], 0, 0, 0);
                acc[1][n] = __builtin_amdgcn_mfma_f32_16x16x32_bf16(a1, b, acc[1][n], 0, 0, 0);
            }
        }

        // epilogue: out = relu(acc + b2)
#pragma unroll
        for (int m = 0; m < 2; m++)
#pragma unroll
            for (int n = 0; n < 8; n++)
#pragma unroll
                for (int ri = 0; ri < 4; ri++) {
                    int e = g * 32 + m*16 + krow * 4 + ri;
                    if (e < E) out[(long long)e * D + n*16 + col0] = fmaxf(acc[m][n][ri] + bias2[n], 0.f);
                }

        g = gn; sidxN = sidx2; didxN = didx2;
    }
}

extern "C" void kernel_launch(void* const* d_in, const int* in_sizes, int n_in,
                              void* d_out, int out_size, void* d_ws, size_t ws_size,
                              hipStream_t stream) {
    const float* x  = (const float*)d_in[0];
    const float* ea = (const float*)d_in[1];
    const int*   ei = (const int*)d_in[2];
    const float* W1 = (const float*)d_in[3];
    const float* b1 = (const float*)d_in[4];
    const float* W2 = (const float*)d_in[5];
    const float* b2 = (const float*)d_in[6];
    float* out = (float*)d_out;

    const int E = in_sizes[1] / D;      // 400000
    const int N = in_sizes[0] / D;      // 50000

    bf16_t* wsl = (bf16_t*)d_ws;                  // 128 KB: 4 transposed weight slices
    bf16_t* uu  = wsl + 4 * 16384;                // N*128 bf16
    bf16_t* vv  = uu + (size_t)N * D;             // N*128 bf16

    prep_weights_kernel<<<256, 256, 0, stream>>>(W1, W2, wsl);

    hipFuncSetAttribute(reinterpret_cast<const void*>(uv_kernel),
                        hipFuncAttributeMaxDynamicSharedMemorySize, UV_LDS);
    hipFuncSetAttribute(reinterpret_cast<const void*>(edge_kernel),
                        hipFuncAttributeMaxDynamicSharedMemorySize, EDGE_LDS);

    uv_kernel<<<(N + 255) / 256, 512, UV_LDS, stream>>>(x, wsl, b1, uu, vv, N);

    edge_kernel<<<256, 512, EDGE_LDS, stream>>>(uu, vv, ea, ei, wsl, b2, out, E);
}

// Round 13
// 328.445 us; speedup vs baseline: 1.2000x; 1.2000x over previous
//
#include <hip/hip_runtime.h>
#include <hip/hip_bf16.h>

typedef __bf16 bf16_t;
typedef __bf16 bf16x8 __attribute__((ext_vector_type(8)));
typedef __bf16 bf16x4 __attribute__((ext_vector_type(4)));
typedef float  f32x4  __attribute__((ext_vector_type(4)));

#define D 128
#define UV_LDS   131072   // uv_kernel: 64KB weights + 8 x 8KB chunks
#define EDGE_LDS 131072   // edge_kernel: 64KB weights + 16 x 4KB chunks

// LDS element-index swizzle: XOR multiples of 8 elems (16B) keep 8-elem groups intact.
__device__ __forceinline__ int swz(int r, int c) {
    return (r * D + c) ^ ((r & 7) << 3);
}

// 4 transposed bf16 weight slices: s<3: ws[s][n][k]=W1[(s*128+k)*128+n]; s==3: W2[k*128+n]
__global__ void prep_weights_kernel(const float* __restrict__ W1,
                                    const float* __restrict__ W2,
                                    bf16_t* __restrict__ ws) {
    int t = blockIdx.x * 256 + threadIdx.x;
    int s = t >> 14, r = t & 16383;
    int n = r >> 7, k = r & 127;
    float v = (s < 3) ? W1[(s * 128 + k) * 128 + n] : W2[k * 128 + n];
    ws[t] = (bf16_t)v;
}

// u = x·W1a + b1, v = x·W1b   (bf16 row-major outputs, gather-ready)
__global__ __launch_bounds__(512, 2)
void uv_kernel(const float* __restrict__ x, const bf16_t* __restrict__ ws,
               const float* __restrict__ b1, bf16_t* __restrict__ u,
               bf16_t* __restrict__ v, int N) {
    extern __shared__ __align__(16) bf16_t lds[];
    const int tid = threadIdx.x, lane = tid & 63, wv = tid >> 6;
    const int col0 = lane & 15, krow = lane >> 4, l31 = lane & 31, half = lane >> 5;
    const int gr = lane >> 4, gc = (lane & 15) * 8;
    const int n0 = blockIdx.x * 256 + wv * 32;
    bf16_t* Ach = lds + 32768 + wv * 4096;

    f32x4 xb[16];
#pragma unroll
    for (int j = 0; j < 16; j++) {
        int node = min(n0 + j * 2 + half, N - 1);
        xb[j] = *(const f32x4*)(x + (long long)node * D + l31 * 4);
    }
#pragma unroll
    for (int s = 0; s < 2; s++)
#pragma unroll
        for (int j = 0; j < 4; j++) {
            int row = j * 32 + (tid >> 4), slot = (tid & 15) * 8;
            bf16x8 w = *(const bf16x8*)(ws + s * 16384 + row * 128 + slot);
            *(bf16x8*)&lds[s * 16384 + swz(row, slot)] = w;
        }
    float bias1[8];
#pragma unroll
    for (int n = 0; n < 8; n++) bias1[n] = b1[n * 16 + col0];
#pragma unroll
    for (int j = 0; j < 16; j++) {
        f32x4 vv = xb[j];
        bf16x4 hv = { (bf16_t)vv.x, (bf16_t)vv.y, (bf16_t)vv.z, (bf16_t)vv.w };
        *(bf16x4*)&Ach[swz(j * 2 + half, l31 * 4)] = hv;
    }
    __syncthreads();

    f32x4 aU[2][8], aV[2][8];
#pragma unroll
    for (int m = 0; m < 2; m++)
#pragma unroll
        for (int n = 0; n < 8; n++) { aU[m][n] = (f32x4){0,0,0,0}; aV[m][n] = (f32x4){0,0,0,0}; }
#pragma unroll
    for (int kk = 0; kk < 4; kk++) {
        bf16x8 a0 = *(const bf16x8*)&Ach[swz(col0, kk*32 + krow*8)];
        bf16x8 a1 = *(const bf16x8*)&Ach[swz(16 + col0, kk*32 + krow*8)];
#pragma unroll
        for (int n = 0; n < 8; n++) {
            bf16x8 bU = *(const bf16x8*)&lds[swz(n*16 + col0, kk*32 + krow*8)];
            bf16x8 bV = *(const bf16x8*)&lds[16384 + swz(n*16 + col0, kk*32 + krow*8)];
            aU[0][n] = __builtin_amdgcn_mfma_f32_16x16x32_bf16(a0, bU, aU[0][n], 0,0,0);
            aU[1][n] = __builtin_amdgcn_mfma_f32_16x16x32_bf16(a1, bU, aU[1][n], 0,0,0);
            aV[0][n] = __builtin_amdgcn_mfma_f32_16x16x32_bf16(a0, bV, aV[0][n], 0,0,0);
            aV[1][n] = __builtin_amdgcn_mfma_f32_16x16x32_bf16(a1, bV, aV[1][n], 0,0,0);
        }
    }
#pragma unroll
    for (int m = 0; m < 2; m++)
#pragma unroll
        for (int n = 0; n < 8; n++)
#pragma unroll
            for (int ri = 0; ri < 4; ri++)
                Ach[swz(m*16 + krow*4 + ri, n*16 + col0)] = (bf16_t)(aU[m][n][ri] + bias1[n]);
#pragma unroll
    for (int j = 0; j < 8; j++) {
        int r = j * 4 + gr, node = n0 + r;
        if (node < N) *(bf16x8*)(u + (long long)node * D + gc) = *(const bf16x8*)&Ach[swz(r, gc)];
    }
#pragma unroll
    for (int m = 0; m < 2; m++)
#pragma unroll
        for (int n = 0; n < 8; n++)
#pragma unroll
            for (int ri = 0; ri < 4; ri++)
                Ach[swz(m*16 + krow*4 + ri, n*16 + col0)] = (bf16_t)(aV[m][n][ri]);
#pragma unroll
    for (int j = 0; j < 8; j++) {
        int r = j * 4 + gr, node = n0 + r;
        if (node < N) *(bf16x8*)(v + (long long)node * D + gc) = *(const bf16x8*)&Ach[swz(r, gc)];
    }
}

// Persistent: out = relu( relu(ea·W1c + u[src] + v[dst]) · W2 + b2 )
// 256 blocks x 16 waves (4 waves/SIMD); each wave grid-strides 16-edge groups
// with loop-carried prefetch. 16-edge groups keep live regs ~112 (< 128 cap).
__global__ __launch_bounds__(1024, 4)
void edge_kernel(const bf16_t* __restrict__ u, const bf16_t* __restrict__ v,
                 const float* __restrict__ ea, const int* __restrict__ ei,
                 const bf16_t* __restrict__ ws, const float* __restrict__ b2,
                 float* __restrict__ out, int E) {
    extern __shared__ __align__(16) bf16_t lds[];   // [2][128][128] W1c,W2 + [16][16][128]
    const int tid = threadIdx.x, lane = tid & 63, wv = tid >> 6;   // wv 0..15
    const int col0 = lane & 15, krow = lane >> 4, l31 = lane & 31, half = lane >> 5;
    const int gr = lane >> 4, gc = (lane & 15) * 8;
    bf16_t* Ach = lds + 32768 + wv * 2048;

    const int totg = (E + 15) >> 4;        // 25000 groups of 16 edges
    const int gstr = gridDim.x * 16;       // 4096 waves
    int g = blockIdx.x * 16 + wv;

    f32x4  eaR[8];
    bf16x8 uR[4], vR[4];
    int sidxN = 0, didxN = 0;

    // ---- prologue: issue group g's loads + prefetch ei(g+1) ----
    if (g < totg) {
        int er = min(g * 16 + col0, E - 1);
        int sidx = ei[er], didx = ei[E + er];
#pragma unroll
        for (int j = 0; j < 8; j++) {
            int e = min(g * 16 + j * 2 + half, E - 1);
            eaR[j] = *(const f32x4*)(ea + (long long)e * D + l31 * 4);
        }
#pragma unroll
        for (int j = 0; j < 4; j++) { int gi = __shfl(sidx, j * 4 + gr); uR[j] = *(const bf16x8*)(u + (long long)gi * D + gc); }
#pragma unroll
        for (int j = 0; j < 4; j++) { int gi = __shfl(didx, j * 4 + gr); vR[j] = *(const bf16x8*)(v + (long long)gi * D + gc); }
        int gn = g + gstr;
        if (gn < totg) {
            int er2 = min(gn * 16 + col0, E - 1);
            sidxN = ei[er2]; didxN = ei[E + er2];
        }
    }
    // stage W1c (slice2), W2 (slice3) once per kernel (1024 threads: each stages 2KB)
#pragma unroll
    for (int s = 0; s < 2; s++)
#pragma unroll
        for (int j = 0; j < 2; j++) {
            int row = j * 64 + (tid >> 4), slot = (tid & 15) * 8;
            bf16x8 w = *(const bf16x8*)(ws + (2 + s) * 16384 + row * 128 + slot);
            *(bf16x8*)&lds[s * 16384 + swz(row, slot)] = w;
        }
    float bias2[8];
#pragma unroll
    for (int n = 0; n < 8; n++) bias2[n] = b2[n * 16 + col0];
    __syncthreads();   // the only barrier

    while (g < totg) {
        const int gn = g + gstr;

        // ea(g) -> chunk (landed ~1 iteration ago)
#pragma unroll
        for (int j = 0; j < 8; j++) {
            f32x4 vv = eaR[j];
            bf16x4 hv = { (bf16_t)vv.x, (bf16_t)vv.y, (bf16_t)vv.z, (bf16_t)vv.w };
            *(bf16x4*)&Ach[swz(j * 2 + half, l31 * 4)] = hv;
        }
        // issue ea(g+1): in flight until next iteration's top
        if (gn < totg) {
#pragma unroll
            for (int j = 0; j < 8; j++) {
                int e = min(gn * 16 + j * 2 + half, E - 1);
                eaR[j] = *(const f32x4*)(ea + (long long)e * D + l31 * 4);
            }
        }
        // prefetch ei(g+2)
        int sidx2 = 0, didx2 = 0;
        int g2 = gn + gstr;
        if (g2 < totg) {
            int er = min(g2 * 16 + col0, E - 1);
            sidx2 = ei[er]; didx2 = ei[E + er];
        }

        // ---- A1: ea · W1c ----
        f32x4 acc[8];
#pragma unroll
        for (int n = 0; n < 8; n++) acc[n] = (f32x4){0,0,0,0};
#pragma unroll
        for (int kk = 0; kk < 4; kk++) {
            bf16x8 a = *(const bf16x8*)&Ach[swz(col0, kk*32 + krow*8)];
#pragma unroll
            for (int n = 0; n < 8; n++) {
                bf16x8 b = *(const bf16x8*)&lds[swz(n*16 + col0, kk*32 + krow*8)];
                acc[n] = __builtin_amdgcn_mfma_f32_16x16x32_bf16(a, b, acc[n], 0, 0, 0);
            }
        }

        // p = A1 result -> chunk (C-space scalar writes)
#pragma unroll
        for (int n = 0; n < 8; n++)
#pragma unroll
            for (int ri = 0; ri < 4; ri++)
                Ach[swz(krow * 4 + ri, n * 16 + col0)] = (bf16_t)acc[n][ri];

        // h = relu(p + u + v) fused in ROW space (uR/vR already row-space registers)
#pragma unroll
        for (int j = 0; j < 4; j++) {
            bf16x8 p8 = *(const bf16x8*)&Ach[swz(j * 4 + gr, gc)];
            bf16x8 su = uR[j], sv = vR[j], h8;
#pragma unroll
            for (int t = 0; t < 8; t++)
                h8[t] = (bf16_t)fmaxf((float)p8[t] + (float)su[t] + (float)sv[t], 0.f);
            *(bf16x8*)&Ach[swz(j * 4 + gr, gc)] = h8;
        }

        // issue u/v(g+1) gathers (uR/vR now free; consumed next iteration)
        if (gn < totg) {
#pragma unroll
            for (int j = 0; j < 4; j++) { int gi = __shfl(sidxN, j * 4 + gr); uR[j] = *(const bf16x8*)(u + (long long)gi * D + gc); }
#pragma unroll
            for (int j = 0; j < 4; j++) { int gi = __shfl(didxN, j * 4 + gr); vR[j] = *(const bf16x8*)(v + (long long)gi * D + gc); }
        }

        // ---- A2: h · W2 ----
#pragma unroll
        for (int n = 0; n < 8; n++) acc[n] = (f32x4){0,0,0,0};
#pragma unroll
        for (int kk = 0; kk < 4; kk++) {
            bf16x8 a = *(const bf16x8*)&Ach[swz(col0, kk*32 + krow*8)];
#pragma unroll
            for (int n = 0; n < 8; n++) {
                bf16x8 b = *(const bf16x8*)&lds[16384 + swz(n*16 + col0, kk*32 + krow*8)];
                acc[n] = __builtin_amdgcn_mfma_f32_16x16x32_bf16(a, b, acc[n], 0, 0, 0);
            }
        }

        // epilogue: out = relu(acc + b2)
#pragma unroll
        for (int n = 0; n < 8; n++)
#pragma unroll
            for (int ri = 0; ri < 4; ri++) {
                int e = g * 16 + krow * 4 + ri;
                if (e < E) out[(long long)e * D + n*16 + col0] = fmaxf(acc[n][ri] + bias2[n], 0.f);
            }

        g = gn; sidxN = sidx2; didxN = didx2;
    }
}

extern "C" void kernel_launch(void* const* d_in, const int* in_sizes, int n_in,
                              void* d_out, int out_size, void* d_ws, size_t ws_size,
                              hipStream_t stream) {
    const float* x  = (const float*)d_in[0];
    const float* ea = (const float*)d_in[1];
    const int*   ei = (const int*)d_in[2];
    const float* W1 = (const float*)d_in[3];
    const float* b1 = (const float*)d_in[4];
    const float* W2 = (const float*)d_in[5];
    const float* b2 = (const float*)d_in[6];
    float* out = (float*)d_out;

    const int E = in_sizes[1] / D;      // 400000
    const int N = in_sizes[0] / D;      // 50000

    bf16_t* wsl = (bf16_t*)d_ws;                  // 128 KB: 4 transposed weight slices
    bf16_t* uu  = wsl + 4 * 16384;                // N*128 bf16
    bf16_t* vv  = uu + (size_t)N * D;             // N*128 bf16

    prep_weights_kernel<<<256, 256, 0, stream>>>(W1, W2, wsl);

    hipFuncSetAttribute(reinterpret_cast<const void*>(uv_kernel),
                        hipFuncAttributeMaxDynamicSharedMemorySize, UV_LDS);
    hipFuncSetAttribute(reinterpret_cast<const void*>(edge_kernel),
                        hipFuncAttributeMaxDynamicSharedMemorySize, EDGE_LDS);

    uv_kernel<<<(N + 255) / 256, 512, UV_LDS, stream>>>(x, wsl, b1, uu, vv, N);

    edge_kernel<<<256, 1024, EDGE_LDS, stream>>>(uu, vv, ea, ei, wsl, b2, out, E);
}

// Round 14
// 271.203 us; speedup vs baseline: 1.4533x; 1.2111x over previous
//
#include <hip/hip_runtime.h>
#include <hip/hip_bf16.h>

typedef __bf16 bf16_t;
typedef __bf16 bf16x8 __attribute__((ext_vector_type(8)));
typedef __bf16 bf16x4 __attribute__((ext_vector_type(4)));
typedef float  f32x4  __attribute__((ext_vector_type(4)));

#define D 128
#define UV_LDS   131072   // uv_kernel: 64KB weights + 8 x 8KB chunks
#define EDGE_LDS 114688   // edge_kernel: 64KB weights + 12 x 4KB chunks = 112KB

// LDS element-index swizzle: XOR multiples of 8 elems (16B) keep 8-elem groups intact.
__device__ __forceinline__ int swz(int r, int c) {
    return (r * D + c) ^ ((r & 7) << 3);
}

// 4 transposed bf16 weight slices: s<3: ws[s][n][k]=W1[(s*128+k)*128+n]; s==3: W2[k*128+n]
__global__ void prep_weights_kernel(const float* __restrict__ W1,
                                    const float* __restrict__ W2,
                                    bf16_t* __restrict__ ws) {
    int t = blockIdx.x * 256 + threadIdx.x;
    int s = t >> 14, r = t & 16383;
    int n = r >> 7, k = r & 127;
    float v = (s < 3) ? W1[(s * 128 + k) * 128 + n] : W2[k * 128 + n];
    ws[t] = (bf16_t)v;
}

// u = x·W1a + b1, v = x·W1b   (bf16 row-major outputs, gather-ready)
__global__ __launch_bounds__(512, 2)
void uv_kernel(const float* __restrict__ x, const bf16_t* __restrict__ ws,
               const float* __restrict__ b1, bf16_t* __restrict__ u,
               bf16_t* __restrict__ v, int N) {
    extern __shared__ __align__(16) bf16_t lds[];
    const int tid = threadIdx.x, lane = tid & 63, wv = tid >> 6;
    const int col0 = lane & 15, krow = lane >> 4, l31 = lane & 31, half = lane >> 5;
    const int gr = lane >> 4, gc = (lane & 15) * 8;
    const int n0 = blockIdx.x * 256 + wv * 32;
    bf16_t* Ach = lds + 32768 + wv * 4096;

    f32x4 xb[16];
#pragma unroll
    for (int j = 0; j < 16; j++) {
        int node = min(n0 + j * 2 + half, N - 1);
        xb[j] = *(const f32x4*)(x + (long long)node * D + l31 * 4);
    }
#pragma unroll
    for (int s = 0; s < 2; s++)
#pragma unroll
        for (int j = 0; j < 4; j++) {
            int row = j * 32 + (tid >> 4), slot = (tid & 15) * 8;
            bf16x8 w = *(const bf16x8*)(ws + s * 16384 + row * 128 + slot);
            *(bf16x8*)&lds[s * 16384 + swz(row, slot)] = w;
        }
    float bias1[8];
#pragma unroll
    for (int n = 0; n < 8; n++) bias1[n] = b1[n * 16 + col0];
#pragma unroll
    for (int j = 0; j < 16; j++) {
        f32x4 vv = xb[j];
        bf16x4 hv = { (bf16_t)vv.x, (bf16_t)vv.y, (bf16_t)vv.z, (bf16_t)vv.w };
        *(bf16x4*)&Ach[swz(j * 2 + half, l31 * 4)] = hv;
    }
    __syncthreads();

    f32x4 aU[2][8], aV[2][8];
#pragma unroll
    for (int m = 0; m < 2; m++)
#pragma unroll
        for (int n = 0; n < 8; n++) { aU[m][n] = (f32x4){0,0,0,0}; aV[m][n] = (f32x4){0,0,0,0}; }
#pragma unroll
    for (int kk = 0; kk < 4; kk++) {
        bf16x8 a0 = *(const bf16x8*)&Ach[swz(col0, kk*32 + krow*8)];
        bf16x8 a1 = *(const bf16x8*)&Ach[swz(16 + col0, kk*32 + krow*8)];
#pragma unroll
        for (int n = 0; n < 8; n++) {
            bf16x8 bU = *(const bf16x8*)&lds[swz(n*16 + col0, kk*32 + krow*8)];
            bf16x8 bV = *(const bf16x8*)&lds[16384 + swz(n*16 + col0, kk*32 + krow*8)];
            aU[0][n] = __builtin_amdgcn_mfma_f32_16x16x32_bf16(a0, bU, aU[0][n], 0,0,0);
            aU[1][n] = __builtin_amdgcn_mfma_f32_16x16x32_bf16(a1, bU, aU[1][n], 0,0,0);
            aV[0][n] = __builtin_amdgcn_mfma_f32_16x16x32_bf16(a0, bV, aV[0][n], 0,0,0);
            aV[1][n] = __builtin_amdgcn_mfma_f32_16x16x32_bf16(a1, bV, aV[1][n], 0,0,0);
        }
    }
#pragma unroll
    for (int m = 0; m < 2; m++)
#pragma unroll
        for (int n = 0; n < 8; n++)
#pragma unroll
            for (int ri = 0; ri < 4; ri++)
                Ach[swz(m*16 + krow*4 + ri, n*16 + col0)] = (bf16_t)(aU[m][n][ri] + bias1[n]);
#pragma unroll
    for (int j = 0; j < 8; j++) {
        int r = j * 4 + gr, node = n0 + r;
        if (node < N) *(bf16x8*)(u + (long long)node * D + gc) = *(const bf16x8*)&Ach[swz(r, gc)];
    }
#pragma unroll
    for (int m = 0; m < 2; m++)
#pragma unroll
        for (int n = 0; n < 8; n++)
#pragma unroll
            for (int ri = 0; ri < 4; ri++)
                Ach[swz(m*16 + krow*4 + ri, n*16 + col0)] = (bf16_t)(aV[m][n][ri]);
#pragma unroll
    for (int j = 0; j < 8; j++) {
        int r = j * 4 + gr, node = n0 + r;
        if (node < N) *(bf16x8*)(v + (long long)node * D + gc) = *(const bf16x8*)&Ach[swz(r, gc)];
    }
}

// Persistent: out = relu( relu(ea·W1c + u[src] + v[dst]) · W2 + b2 )
// 256 blocks x 12 waves (3 waves/SIMD, 1 block/CU); grid-stride 16-edge groups
// with loop-carried prefetch. launch_bounds(768,1) keeps VGPR cap >= 170.
__global__ __launch_bounds__(768, 1)
void edge_kernel(const bf16_t* __restrict__ u, const bf16_t* __restrict__ v,
                 const float* __restrict__ ea, const int* __restrict__ ei,
                 const bf16_t* __restrict__ ws, const float* __restrict__ b2,
                 float* __restrict__ out, int E) {
    extern __shared__ __align__(16) bf16_t lds[];   // [2][128][128] W1c,W2 + [12][16][128]
    const int tid = threadIdx.x, lane = tid & 63, wv = tid >> 6;   // wv 0..11
    const int col0 = lane & 15, krow = lane >> 4, l31 = lane & 31, half = lane >> 5;
    const int gr = lane >> 4, gc = (lane & 15) * 8;
    bf16_t* Ach = lds + 32768 + wv * 2048;

    const int totg = (E + 15) >> 4;        // 25000 groups of 16 edges
    const int gstr = gridDim.x * 12;       // 3072 waves
    int g = blockIdx.x * 12 + wv;

    f32x4  eaR[8];
    bf16x8 uR[4], vR[4];
    int sidxN = 0, didxN = 0;

    // ---- prologue: issue group g's loads + prefetch ei(g+1) ----
    if (g < totg) {
        int er = min(g * 16 + col0, E - 1);
        int sidx = ei[er], didx = ei[E + er];
#pragma unroll
        for (int j = 0; j < 8; j++) {
            int e = min(g * 16 + j * 2 + half, E - 1);
            eaR[j] = *(const f32x4*)(ea + (long long)e * D + l31 * 4);
        }
#pragma unroll
        for (int j = 0; j < 4; j++) { int gi = __shfl(sidx, j * 4 + gr); uR[j] = *(const bf16x8*)(u + (long long)gi * D + gc); }
#pragma unroll
        for (int j = 0; j < 4; j++) { int gi = __shfl(didx, j * 4 + gr); vR[j] = *(const bf16x8*)(v + (long long)gi * D + gc); }
        int gn = g + gstr;
        if (gn < totg) {
            int er2 = min(gn * 16 + col0, E - 1);
            sidxN = ei[er2]; didxN = ei[E + er2];
        }
    }
    // stage W1c (slice2), W2 (slice3) once per kernel (768 threads, guard row<128)
#pragma unroll
    for (int s = 0; s < 2; s++)
#pragma unroll
        for (int j = 0; j < 3; j++) {
            int row = j * 48 + (tid >> 4), slot = (tid & 15) * 8;
            if (row < 128) {
                bf16x8 w = *(const bf16x8*)(ws + (2 + s) * 16384 + row * 128 + slot);
                *(bf16x8*)&lds[s * 16384 + swz(row, slot)] = w;
            }
        }
    float bias2[8];
#pragma unroll
    for (int n = 0; n < 8; n++) bias2[n] = b2[n * 16 + col0];
    __syncthreads();   // the only barrier

    while (g < totg) {
        const int gn = g + gstr;

        // ea(g) -> chunk (landed ~1 iteration ago)
#pragma unroll
        for (int j = 0; j < 8; j++) {
            f32x4 vv = eaR[j];
            bf16x4 hv = { (bf16_t)vv.x, (bf16_t)vv.y, (bf16_t)vv.z, (bf16_t)vv.w };
            *(bf16x4*)&Ach[swz(j * 2 + half, l31 * 4)] = hv;
        }
        // issue ea(g+1): in flight until next iteration's top
        if (gn < totg) {
#pragma unroll
            for (int j = 0; j < 8; j++) {
                int e = min(gn * 16 + j * 2 + half, E - 1);
                eaR[j] = *(const f32x4*)(ea + (long long)e * D + l31 * 4);
            }
        }
        // prefetch ei(g+2)
        int sidx2 = 0, didx2 = 0;
        int g2 = gn + gstr;
        if (g2 < totg) {
            int er = min(g2 * 16 + col0, E - 1);
            sidx2 = ei[er]; didx2 = ei[E + er];
        }

        // ---- A1: ea · W1c ----
        f32x4 acc[8];
#pragma unroll
        for (int n = 0; n < 8; n++) acc[n] = (f32x4){0,0,0,0};
#pragma unroll
        for (int kk = 0; kk < 4; kk++) {
            bf16x8 a = *(const bf16x8*)&Ach[swz(col0, kk*32 + krow*8)];
#pragma unroll
            for (int n = 0; n < 8; n++) {
                bf16x8 b = *(const bf16x8*)&lds[swz(n*16 + col0, kk*32 + krow*8)];
                acc[n] = __builtin_amdgcn_mfma_f32_16x16x32_bf16(a, b, acc[n], 0, 0, 0);
            }
        }

        // p = A1 result -> chunk (C-space scalar writes)
#pragma unroll
        for (int n = 0; n < 8; n++)
#pragma unroll
            for (int ri = 0; ri < 4; ri++)
                Ach[swz(krow * 4 + ri, n * 16 + col0)] = (bf16_t)acc[n][ri];

        // h = relu(p + u + v) fused in ROW space (uR/vR already row-space registers)
#pragma unroll
        for (int j = 0; j < 4; j++) {
            bf16x8 p8 = *(const bf16x8*)&Ach[swz(j * 4 + gr, gc)];
            bf16x8 su = uR[j], sv = vR[j], h8;
#pragma unroll
            for (int t = 0; t < 8; t++)
                h8[t] = (bf16_t)fmaxf((float)p8[t] + (float)su[t] + (float)sv[t], 0.f);
            *(bf16x8*)&Ach[swz(j * 4 + gr, gc)] = h8;
        }

        // issue u/v(g+1) gathers (uR/vR now free; consumed next iteration)
        if (gn < totg) {
#pragma unroll
            for (int j = 0; j < 4; j++) { int gi = __shfl(sidxN, j * 4 + gr); uR[j] = *(const bf16x8*)(u + (long long)gi * D + gc); }
#pragma unroll
            for (int j = 0; j < 4; j++) { int gi = __shfl(didxN, j * 4 + gr); vR[j] = *(const bf16x8*)(v + (long long)gi * D + gc); }
        }

        // ---- A2: h · W2 ----
#pragma unroll
        for (int n = 0; n < 8; n++) acc[n] = (f32x4){0,0,0,0};
#pragma unroll
        for (int kk = 0; kk < 4; kk++) {
            bf16x8 a = *(const bf16x8*)&Ach[swz(col0, kk*32 + krow*8)];
#pragma unroll
            for (int n = 0; n < 8; n++) {
                bf16x8 b = *(const bf16x8*)&lds[16384 + swz(n*16 + col0, kk*32 + krow*8)];
                acc[n] = __builtin_amdgcn_mfma_f32_16x16x32_bf16(a, b, acc[n], 0, 0, 0);
            }
        }

        // epilogue: out = relu(acc + b2)
#pragma unroll
        for (int n = 0; n < 8; n++)
#pragma unroll
            for (int ri = 0; ri < 4; ri++) {
                int e = g * 16 + krow * 4 + ri;
                if (e < E) out[(long long)e * D + n*16 + col0] = fmaxf(acc[n][ri] + bias2[n], 0.f);
            }

        g = gn; sidxN = sidx2; didxN = didx2;
    }
}

extern "C" void kernel_launch(void* const* d_in, const int* in_sizes, int n_in,
                              void* d_out, int out_size, void* d_ws, size_t ws_size,
                              hipStream_t stream) {
    const float* x  = (const float*)d_in[0];
    const float* ea = (const float*)d_in[1];
    const int*   ei = (const int*)d_in[2];
    const float* W1 = (const float*)d_in[3];
    const float* b1 = (const float*)d_in[4];
    const float* W2 = (const float*)d_in[5];
    const float* b2 = (const float*)d_in[6];
    float* out = (float*)d_out;

    const int E = in_sizes[1] / D;      // 400000
    const int N = in_sizes[0] / D;      // 50000

    bf16_t* wsl = (bf16_t*)d_ws;                  // 128 KB: 4 transposed weight slices
    bf16_t* uu  = wsl + 4 * 16384;                // N*128 bf16
    bf16_t* vv  = uu + (size_t)N * D;             // N*128 bf16

    prep_weights_kernel<<<256, 256, 0, stream>>>(W1, W2, wsl);

    hipFuncSetAttribute(reinterpret_cast<const void*>(uv_kernel),
                        hipFuncAttributeMaxDynamicSharedMemorySize, UV_LDS);
    hipFuncSetAttribute(reinterpret_cast<const void*>(edge_kernel),
                        hipFuncAttributeMaxDynamicSharedMemorySize, EDGE_LDS);

    uv_kernel<<<(N + 255) / 256, 512, UV_LDS, stream>>>(x, wsl, b1, uu, vv, N);

    edge_kernel<<<256, 768, EDGE_LDS, stream>>>(uu, vv, ea, ei, wsl, b2, out, E);
}

// Round 16
// 152.374 us; speedup vs baseline: 2.5866x; 1.7799x over previous
//
#include <hip/hip_runtime.h>
#include <hip/hip_bf16.h>

typedef __bf16 bf16_t;
typedef __bf16 bf16x8 __attribute__((ext_vector_type(8)));
typedef __bf16 bf16x4 __attribute__((ext_vector_type(4)));
typedef float  f32x4  __attribute__((ext_vector_type(4)));

#define D 128
#define UV_LDS 131072   // uv_kernel: 64KB weights + 8 x 8KB chunks

// LDS element-index swizzle: XOR multiples of 8 elems (16B) keep 4/8-elem groups intact.
__device__ __forceinline__ int swz(int r, int c) {
    return (r * D + c) ^ ((r & 7) << 3);
}

// prep: blocks 0..255: 4 transposed slice-major weight tiles ws[s][c][k]
//       blocks 256..271: fragment-packed W1c/W2 for the edge kernel:
//       wsf[((g*4+kk)*8+n)*64 + lane] (bf16x8) = Wt_g[n*16+(lane&15)][kk*32+(lane>>4)*8 ..+8]
__global__ void prep_weights_kernel(const float* __restrict__ W1,
                                    const float* __restrict__ W2,
                                    bf16_t* __restrict__ ws,
                                    bf16_t* __restrict__ wsf) {
    int b = blockIdx.x;
    if (b < 256) {
        int t = b * 256 + threadIdx.x;
        int s = t >> 14, r = t & 16383;
        int n = r >> 7, k = r & 127;
        float v = (s < 3) ? W1[(s * 128 + k) * 128 + n] : W2[k * 128 + n];
        ws[t] = (bf16_t)v;
    } else {
        int t = (b - 256) * 256 + threadIdx.x;      // 0..4095
        int lane = t & 63, f = t >> 6;              // f = (g*4+kk)*8+n
        int n = f & 7, kk = (f >> 3) & 3, g = f >> 5;
        int c = n * 16 + (lane & 15);
        int k0 = kk * 32 + (lane >> 4) * 8;
        bf16x8 v;
#pragma unroll
        for (int j = 0; j < 8; j++) {
            int k = k0 + j;
            float w = (g == 0) ? W1[(256 + k) * 128 + c] : W2[k * 128 + c];
            v[j] = (bf16_t)w;
        }
        *(bf16x8*)(wsf + t * 8) = v;
    }
}

// u = x·W1a + b1, v = x·W1b   (bf16 row-major, gather-ready)  [proven R10 kernel]
__global__ __launch_bounds__(512, 2)
void uv_kernel(const float* __restrict__ x, const bf16_t* __restrict__ ws,
               const float* __restrict__ b1, bf16_t* __restrict__ u,
               bf16_t* __restrict__ v, int N) {
    extern __shared__ __align__(16) bf16_t lds[];
    const int tid = threadIdx.x, lane = tid & 63, wv = tid >> 6;
    const int col0 = lane & 15, krow = lane >> 4, l31 = lane & 31, half = lane >> 5;
    const int gr = lane >> 4, gc = (lane & 15) * 8;
    const int n0 = blockIdx.x * 256 + wv * 32;
    bf16_t* Ach = lds + 32768 + wv * 4096;

    f32x4 xb[16];
#pragma unroll
    for (int j = 0; j < 16; j++) {
        int node = min(n0 + j * 2 + half, N - 1);
        xb[j] = *(const f32x4*)(x + (long long)node * D + l31 * 4);
    }
#pragma unroll
    for (int s = 0; s < 2; s++)
#pragma unroll
        for (int j = 0; j < 4; j++) {
            int row = j * 32 + (tid >> 4), slot = (tid & 15) * 8;
            bf16x8 w = *(const bf16x8*)(ws + s * 16384 + row * 128 + slot);
            *(bf16x8*)&lds[s * 16384 + swz(row, slot)] = w;
        }
    float bias1[8];
#pragma unroll
    for (int n = 0; n < 8; n++) bias1[n] = b1[n * 16 + col0];
#pragma unroll
    for (int j = 0; j < 16; j++) {
        f32x4 vv = xb[j];
        bf16x4 hv = { (bf16_t)vv.x, (bf16_t)vv.y, (bf16_t)vv.z, (bf16_t)vv.w };
        *(bf16x4*)&Ach[swz(j * 2 + half, l31 * 4)] = hv;
    }
    __syncthreads();

    f32x4 aU[2][8], aV[2][8];
#pragma unroll
    for (int m = 0; m < 2; m++)
#pragma unroll
        for (int n = 0; n < 8; n++) { aU[m][n] = (f32x4){0,0,0,0}; aV[m][n] = (f32x4){0,0,0,0}; }
#pragma unroll
    for (int kk = 0; kk < 4; kk++) {
        bf16x8 a0 = *(const bf16x8*)&Ach[swz(col0, kk*32 + krow*8)];
        bf16x8 a1 = *(const bf16x8*)&Ach[swz(16 + col0, kk*32 + krow*8)];
#pragma unroll
        for (int n = 0; n < 8; n++) {
            bf16x8 bU = *(const bf16x8*)&lds[swz(n*16 + col0, kk*32 + krow*8)];
            bf16x8 bV = *(const bf16x8*)&lds[16384 + swz(n*16 + col0, kk*32 + krow*8)];
            aU[0][n] = __builtin_amdgcn_mfma_f32_16x16x32_bf16(a0, bU, aU[0][n], 0,0,0);
            aU[1][n] = __builtin_amdgcn_mfma_f32_16x16x32_bf16(a1, bU, aU[1][n], 0,0,0);
            aV[0][n] = __builtin_amdgcn_mfma_f32_16x16x32_bf16(a0, bV, aV[0][n], 0,0,0);
            aV[1][n] = __builtin_amdgcn_mfma_f32_16x16x32_bf16(a1, bV, aV[1][n], 0,0,0);
        }
    }
#pragma unroll
    for (int m = 0; m < 2; m++)
#pragma unroll
        for (int n = 0; n < 8; n++)
#pragma unroll
            for (int ri = 0; ri < 4; ri++)
                Ach[swz(m*16 + krow*4 + ri, n*16 + col0)] = (bf16_t)(aU[m][n][ri] + bias1[n]);
#pragma unroll
    for (int j = 0; j < 8; j++) {
        int r = j * 4 + gr, node = n0 + r;
        if (node < N) *(bf16x8*)(u + (long long)node * D + gc) = *(const bf16x8*)&Ach[swz(r, gc)];
    }
#pragma unroll
    for (int m = 0; m < 2; m++)
#pragma unroll
        for (int n = 0; n < 8; n++)
#pragma unroll
            for (int ri = 0; ri < 4; ri++)
                Ach[swz(m*16 + krow*4 + ri, n*16 + col0)] = (bf16_t)(aV[m][n][ri]);
#pragma unroll
    for (int j = 0; j < 8; j++) {
        int r = j * 4 + gr, node = n0 + r;
        if (node < N) *(bf16x8*)(v + (long long)node * D + gc) = *(const bf16x8*)&Ach[swz(r, gc)];
    }
}

// Cooperative 32-edge tile, 4 waves; wave wv owns output cols [wv*32, wv*32+32).
// B-fragments (W1c, W2) live in registers; LDS = two 8KB chunks only.
// out = relu( relu(ea·W1c + u[src] + v[dst]) · W2 + b2 )
__global__ __launch_bounds__(256, 3)
void edge_kernel(const bf16_t* __restrict__ u, const bf16_t* __restrict__ v,
                 const float* __restrict__ ea, const int* __restrict__ ei,
                 const bf16_t* __restrict__ wsf, const float* __restrict__ b2,
                 float* __restrict__ out, int E) {
    __shared__ __align__(16) bf16_t Ach[32 * D];   // ea tile (bf16, swizzled)
    __shared__ __align__(16) bf16_t Hch[32 * D];   // p then h tile

    const int tid  = threadIdx.x, lane = tid & 63, wv = tid >> 6;   // 4 waves
    const int col0 = lane & 15, krow = lane >> 4, l31 = lane & 31;
    const int e0   = blockIdx.x * 32;

    // ---- issue ea loads for my 8 rows (2 contiguous 512B rows per instr) ----
    f32x4 eaR[4];
#pragma unroll
    for (int j = 0; j < 4; j++) {
        int r = wv * 8 + j * 2 + (lane >> 5);
        int e = min(e0 + r, E - 1);
        eaR[j] = *(const f32x4*)(ea + (long long)e * D + l31 * 4);
    }
    // ---- indices for my 8 rows (lane q<8 holds row q), then u/v gathers ----
    const int er8 = min(e0 + wv * 8 + (lane & 7), E - 1);
    const int sidx = ei[er8];
    const int didx = ei[E + er8];
    bf16x8 uR[2], vR[2];
#pragma unroll
    for (int j = 0; j < 2; j++) {
        int gi = __shfl(sidx, j * 4 + (lane >> 4));   // 4 rows/instr, 256B per row
        uR[j] = *(const bf16x8*)(u + (long long)gi * D + col0 * 8);
    }
#pragma unroll
    for (int j = 0; j < 2; j++) {
        int gi = __shfl(didx, j * 4 + (lane >> 4));
        vR[j] = *(const bf16x8*)(v + (long long)gi * D + col0 * 8);
    }

    // ---- B fragments for my 2 column-frags (1KB contiguous per load, L2-hot) ----
    // W1c = fragments (0*4+kk)*8+n ; W2 = fragments (4+kk)*8+n   [fixed R15 bug]
    bf16x8 B1[4][2], B2[4][2];
#pragma unroll
    for (int kk = 0; kk < 4; kk++)
#pragma unroll
        for (int j = 0; j < 2; j++) {
            B1[kk][j] = *(const bf16x8*)(wsf + (((kk)     * 8 + (wv * 2 + j)) * 64 + lane) * 8);
            B2[kk][j] = *(const bf16x8*)(wsf + (((4 + kk) * 8 + (wv * 2 + j)) * 64 + lane) * 8);
        }
    float bias2[2];
    bias2[0] = b2[wv * 32 + col0];
    bias2[1] = b2[wv * 32 + 16 + col0];

    // ---- ea -> Ach (bf16, swizzled) ----
#pragma unroll
    for (int j = 0; j < 4; j++) {
        int r = wv * 8 + j * 2 + (lane >> 5);
        f32x4 vv = eaR[j];
        bf16x4 hv = { (bf16_t)vv.x, (bf16_t)vv.y, (bf16_t)vv.z, (bf16_t)vv.w };
        *(bf16x4*)&Ach[swz(r, l31 * 4)] = hv;
    }
    __syncthreads();

    // ---- A1: p = ea · W1c  (my 32 cols) ----
    f32x4 acc[2][2];
#pragma unroll
    for (int m = 0; m < 2; m++)
#pragma unroll
        for (int j = 0; j < 2; j++) acc[m][j] = (f32x4){0,0,0,0};
#pragma unroll
    for (int kk = 0; kk < 4; kk++) {
        bf16x8 a0 = *(const bf16x8*)&Ach[swz(     col0, kk*32 + krow*8)];
        bf16x8 a1 = *(const bf16x8*)&Ach[swz(16 + col0, kk*32 + krow*8)];
#pragma unroll
        for (int j = 0; j < 2; j++) {
            acc[0][j] = __builtin_amdgcn_mfma_f32_16x16x32_bf16(a0, B1[kk][j], acc[0][j], 0,0,0);
            acc[1][j] = __builtin_amdgcn_mfma_f32_16x16x32_bf16(a1, B1[kk][j], acc[1][j], 0,0,0);
        }
    }
    // p -> Hch (C-space scalar writes; cols wv*32..+32, rows 0..31)
#pragma unroll
    for (int m = 0; m < 2; m++)
#pragma unroll
        for (int j = 0; j < 2; j++)
#pragma unroll
            for (int ri = 0; ri < 4; ri++)
                Hch[swz(m*16 + krow*4 + ri, wv*32 + j*16 + col0)] = (bf16_t)acc[m][j][ri];
    __syncthreads();

    // ---- h = relu(p + u + v) for my 8 rows, fused in registers ----
#pragma unroll
    for (int j = 0; j < 2; j++) {
        int r = wv * 8 + j * 4 + (lane >> 4);
        bf16x8 p8 = *(const bf16x8*)&Hch[swz(r, col0 * 8)];
        bf16x8 h8;
#pragma unroll
        for (int t = 0; t < 8; t++)
            h8[t] = (bf16_t)fmaxf((float)p8[t] + (float)uR[j][t] + (float)vR[j][t], 0.f);
        *(bf16x8*)&Hch[swz(r, col0 * 8)] = h8;
    }
    __syncthreads();

    // ---- A2: out = h · W2  (my 32 cols) ----
#pragma unroll
    for (int m = 0; m < 2; m++)
#pragma unroll
        for (int j = 0; j < 2; j++) acc[m][j] = (f32x4){0,0,0,0};
#pragma unroll
    for (int kk = 0; kk < 4; kk++) {
        bf16x8 a0 = *(const bf16x8*)&Hch[swz(     col0, kk*32 + krow*8)];
        bf16x8 a1 = *(const bf16x8*)&Hch[swz(16 + col0, kk*32 + krow*8)];
#pragma unroll
        for (int j = 0; j < 2; j++) {
            acc[0][j] = __builtin_amdgcn_mfma_f32_16x16x32_bf16(a0, B2[kk][j], acc[0][j], 0,0,0);
            acc[1][j] = __builtin_amdgcn_mfma_f32_16x16x32_bf16(a1, B2[kk][j], acc[1][j], 0,0,0);
        }
    }
    // epilogue: out = relu(acc + b2)
#pragma unroll
    for (int m = 0; m < 2; m++)
#pragma unroll
        for (int j = 0; j < 2; j++)
#pragma unroll
            for (int ri = 0; ri < 4; ri++) {
                int e = e0 + m*16 + krow*4 + ri;
                if (e < E)
                    out[(long long)e * D + wv*32 + j*16 + col0] = fmaxf(acc[m][j][ri] + bias2[j], 0.f);
            }
}

extern "C" void kernel_launch(void* const* d_in, const int* in_sizes, int n_in,
                              void* d_out, int out_size, void* d_ws, size_t ws_size,
                              hipStream_t stream) {
    const float* x  = (const float*)d_in[0];
    const float* ea = (const float*)d_in[1];
    const int*   ei = (const int*)d_in[2];
    const float* W1 = (const float*)d_in[3];
    const float* b1 = (const float*)d_in[4];
    const float* W2 = (const float*)d_in[5];
    const float* b2 = (const float*)d_in[6];
    float* out = (float*)d_out;

    const int E = in_sizes[1] / D;      // 400000
    const int N = in_sizes[0] / D;      // 50000

    bf16_t* wsl = (bf16_t*)d_ws;                  // 128 KB: slice-major tiles (uv_kernel)
    bf16_t* wsf = wsl + 4 * 16384;                // 64 KB: fragment-packed W1c/W2 (edge)
    bf16_t* uu  = wsf + 32768;                    // N*128 bf16
    bf16_t* vv  = uu + (size_t)N * D;             // N*128 bf16

    prep_weights_kernel<<<272, 256, 0, stream>>>(W1, W2, wsl, wsf);

    hipFuncSetAttribute(reinterpret_cast<const void*>(uv_kernel),
                        hipFuncAttributeMaxDynamicSharedMemorySize, UV_LDS);
    uv_kernel<<<(N + 255) / 256, 512, UV_LDS, stream>>>(x, wsl, b1, uu, vv, N);

    int nblocks = (E + 31) / 32;                  // 12500
    edge_kernel<<<nblocks, 256, 0, stream>>>(uu, vv, ea, ei, wsf, b2, out, E);
}

// Round 17
// 121.785 us; speedup vs baseline: 3.2363x; 1.2512x over previous
//
#include <hip/hip_runtime.h>
#include <hip/hip_bf16.h>

typedef __bf16 bf16_t;
typedef __bf16 bf16x8 __attribute__((ext_vector_type(8)));
typedef __bf16 bf16x4 __attribute__((ext_vector_type(4)));
typedef float  f32x4  __attribute__((ext_vector_type(4)));

#define D 128
#define UV_LDS 131072   // uv_kernel: 64KB weights + 8 x 8KB chunks

// LDS element-index swizzle: XOR multiples of 8 elems (16B) keep 4/8-elem groups intact.
__device__ __forceinline__ int swz(int r, int c) {
    return (r * D + c) ^ ((r & 7) << 3);
}

// prep: blocks 0..255: 4 transposed slice-major weight tiles ws[s][c][k]
//       blocks 256..271: fragment-packed W1c/W2 for the edge kernel:
//       wsf[((g*4+kk)*8+n)*64 + lane] (bf16x8) = Wt_g[n*16+(lane&15)][kk*32+(lane>>4)*8 ..+8]
__global__ void prep_weights_kernel(const float* __restrict__ W1,
                                    const float* __restrict__ W2,
                                    bf16_t* __restrict__ ws,
                                    bf16_t* __restrict__ wsf) {
    int b = blockIdx.x;
    if (b < 256) {
        int t = b * 256 + threadIdx.x;
        int s = t >> 14, r = t & 16383;
        int n = r >> 7, k = r & 127;
        float v = (s < 3) ? W1[(s * 128 + k) * 128 + n] : W2[k * 128 + n];
        ws[t] = (bf16_t)v;
    } else {
        int t = (b - 256) * 256 + threadIdx.x;      // 0..4095
        int lane = t & 63, f = t >> 6;              // f = (g*4+kk)*8+n
        int n = f & 7, kk = (f >> 3) & 3, g = f >> 5;
        int c = n * 16 + (lane & 15);
        int k0 = kk * 32 + (lane >> 4) * 8;
        bf16x8 v;
#pragma unroll
        for (int j = 0; j < 8; j++) {
            int k = k0 + j;
            float w = (g == 0) ? W1[(256 + k) * 128 + c] : W2[k * 128 + c];
            v[j] = (bf16_t)w;
        }
        *(bf16x8*)(wsf + t * 8) = v;
    }
}

// u = x·W1a + b1, v = x·W1b   (bf16 row-major, gather-ready)  [proven R10 kernel]
__global__ __launch_bounds__(512, 2)
void uv_kernel(const float* __restrict__ x, const bf16_t* __restrict__ ws,
               const float* __restrict__ b1, bf16_t* __restrict__ u,
               bf16_t* __restrict__ v, int N) {
    extern __shared__ __align__(16) bf16_t lds[];
    const int tid = threadIdx.x, lane = tid & 63, wv = tid >> 6;
    const int col0 = lane & 15, krow = lane >> 4, l31 = lane & 31, half = lane >> 5;
    const int gr = lane >> 4, gc = (lane & 15) * 8;
    const int n0 = blockIdx.x * 256 + wv * 32;
    bf16_t* Ach = lds + 32768 + wv * 4096;

    f32x4 xb[16];
#pragma unroll
    for (int j = 0; j < 16; j++) {
        int node = min(n0 + j * 2 + half, N - 1);
        xb[j] = *(const f32x4*)(x + (long long)node * D + l31 * 4);
    }
#pragma unroll
    for (int s = 0; s < 2; s++)
#pragma unroll
        for (int j = 0; j < 4; j++) {
            int row = j * 32 + (tid >> 4), slot = (tid & 15) * 8;
            bf16x8 w = *(const bf16x8*)(ws + s * 16384 + row * 128 + slot);
            *(bf16x8*)&lds[s * 16384 + swz(row, slot)] = w;
        }
    float bias1[8];
#pragma unroll
    for (int n = 0; n < 8; n++) bias1[n] = b1[n * 16 + col0];
#pragma unroll
    for (int j = 0; j < 16; j++) {
        f32x4 vv = xb[j];
        bf16x4 hv = { (bf16_t)vv.x, (bf16_t)vv.y, (bf16_t)vv.z, (bf16_t)vv.w };
        *(bf16x4*)&Ach[swz(j * 2 + half, l31 * 4)] = hv;
    }
    __syncthreads();

    f32x4 aU[2][8], aV[2][8];
#pragma unroll
    for (int m = 0; m < 2; m++)
#pragma unroll
        for (int n = 0; n < 8; n++) { aU[m][n] = (f32x4){0,0,0,0}; aV[m][n] = (f32x4){0,0,0,0}; }
#pragma unroll
    for (int kk = 0; kk < 4; kk++) {
        bf16x8 a0 = *(const bf16x8*)&Ach[swz(col0, kk*32 + krow*8)];
        bf16x8 a1 = *(const bf16x8*)&Ach[swz(16 + col0, kk*32 + krow*8)];
#pragma unroll
        for (int n = 0; n < 8; n++) {
            bf16x8 bU = *(const bf16x8*)&lds[swz(n*16 + col0, kk*32 + krow*8)];
            bf16x8 bV = *(const bf16x8*)&lds[16384 + swz(n*16 + col0, kk*32 + krow*8)];
            aU[0][n] = __builtin_amdgcn_mfma_f32_16x16x32_bf16(a0, bU, aU[0][n], 0,0,0);
            aU[1][n] = __builtin_amdgcn_mfma_f32_16x16x32_bf16(a1, bU, aU[1][n], 0,0,0);
            aV[0][n] = __builtin_amdgcn_mfma_f32_16x16x32_bf16(a0, bV, aV[0][n], 0,0,0);
            aV[1][n] = __builtin_amdgcn_mfma_f32_16x16x32_bf16(a1, bV, aV[1][n], 0,0,0);
        }
    }
#pragma unroll
    for (int m = 0; m < 2; m++)
#pragma unroll
        for (int n = 0; n < 8; n++)
#pragma unroll
            for (int ri = 0; ri < 4; ri++)
                Ach[swz(m*16 + krow*4 + ri, n*16 + col0)] = (bf16_t)(aU[m][n][ri] + bias1[n]);
#pragma unroll
    for (int j = 0; j < 8; j++) {
        int r = j * 4 + gr, node = n0 + r;
        if (node < N) *(bf16x8*)(u + (long long)node * D + gc) = *(const bf16x8*)&Ach[swz(r, gc)];
    }
#pragma unroll
    for (int m = 0; m < 2; m++)
#pragma unroll
        for (int n = 0; n < 8; n++)
#pragma unroll
            for (int ri = 0; ri < 4; ri++)
                Ach[swz(m*16 + krow*4 + ri, n*16 + col0)] = (bf16_t)(aV[m][n][ri]);
#pragma unroll
    for (int j = 0; j < 8; j++) {
        int r = j * 4 + gr, node = n0 + r;
        if (node < N) *(bf16x8*)(v + (long long)node * D + gc) = *(const bf16x8*)&Ach[swz(r, gc)];
    }
}

// Two independent 32-edge tiles per block (phase-interleaved for ILP), 4 waves;
// wave wv owns output cols [wv*32, wv*32+32) of both tiles. B-fragments in regs.
// out = relu( relu(ea·W1c + u[src] + v[dst]) · W2 + b2 )
__global__ __launch_bounds__(256, 3)
void edge_kernel(const bf16_t* __restrict__ u, const bf16_t* __restrict__ v,
                 const float* __restrict__ ea, const int* __restrict__ ei,
                 const bf16_t* __restrict__ wsf, const float* __restrict__ b2,
                 float* __restrict__ out, int E) {
    __shared__ __align__(16) bf16_t Ach[2][32 * D];   // ea tiles (bf16, swizzled)
    __shared__ __align__(16) bf16_t Hch[2][32 * D];   // p then h tiles

    const int tid  = threadIdx.x, lane = tid & 63, wv = tid >> 6;   // 4 waves
    const int col0 = lane & 15, krow = lane >> 4, l31 = lane & 31;
    const int e0   = blockIdx.x * 64;                // tile c: rows e0 + c*32 ..

    // ---- issue ea loads for my 8 rows of BOTH tiles ----
    f32x4 eaR[2][4];
#pragma unroll
    for (int c = 0; c < 2; c++)
#pragma unroll
        for (int j = 0; j < 4; j++) {
            int r = wv * 8 + j * 2 + (lane >> 5);
            int e = min(e0 + c * 32 + r, E - 1);
            eaR[c][j] = *(const f32x4*)(ea + (long long)e * D + l31 * 4);
        }
    // ---- indices + u/v gathers for both tiles ----
    int sidx[2], didx[2];
#pragma unroll
    for (int c = 0; c < 2; c++) {
        int er8 = min(e0 + c * 32 + wv * 8 + (lane & 7), E - 1);
        sidx[c] = ei[er8];
        didx[c] = ei[E + er8];
    }
    bf16x8 uR[2][2], vR[2][2];
#pragma unroll
    for (int c = 0; c < 2; c++)
#pragma unroll
        for (int j = 0; j < 2; j++) {
            int gi = __shfl(sidx[c], j * 4 + (lane >> 4));   // 4 rows/instr, 256B/row
            uR[c][j] = *(const bf16x8*)(u + (long long)gi * D + col0 * 8);
            int gj = __shfl(didx[c], j * 4 + (lane >> 4));
            vR[c][j] = *(const bf16x8*)(v + (long long)gj * D + col0 * 8);
        }

    // ---- B fragments for my 2 column-frags (1KB contiguous, L2-hot) ----
    bf16x8 B1[4][2], B2[4][2];
#pragma unroll
    for (int kk = 0; kk < 4; kk++)
#pragma unroll
        for (int j = 0; j < 2; j++) {
            B1[kk][j] = *(const bf16x8*)(wsf + (((kk)     * 8 + (wv * 2 + j)) * 64 + lane) * 8);
            B2[kk][j] = *(const bf16x8*)(wsf + (((4 + kk) * 8 + (wv * 2 + j)) * 64 + lane) * 8);
        }
    float bias2[2];
    bias2[0] = b2[wv * 32 + col0];
    bias2[1] = b2[wv * 32 + 16 + col0];

    // ---- ea -> Ach (both tiles) ----
#pragma unroll
    for (int c = 0; c < 2; c++)
#pragma unroll
        for (int j = 0; j < 4; j++) {
            int r = wv * 8 + j * 2 + (lane >> 5);
            f32x4 vv = eaR[c][j];
            bf16x4 hv = { (bf16_t)vv.x, (bf16_t)vv.y, (bf16_t)vv.z, (bf16_t)vv.w };
            *(bf16x4*)&Ach[c][swz(r, l31 * 4)] = hv;
        }
    __syncthreads();

    // ---- A1 both tiles: p = ea · W1c  (independent -> interleaved by scheduler) ----
    f32x4 acc[2][2][2];   // [tile][m][j]
#pragma unroll
    for (int c = 0; c < 2; c++)
#pragma unroll
        for (int m = 0; m < 2; m++)
#pragma unroll
            for (int j = 0; j < 2; j++) acc[c][m][j] = (f32x4){0,0,0,0};
#pragma unroll
    for (int kk = 0; kk < 4; kk++) {
#pragma unroll
        for (int c = 0; c < 2; c++) {
            bf16x8 a0 = *(const bf16x8*)&Ach[c][swz(     col0, kk*32 + krow*8)];
            bf16x8 a1 = *(const bf16x8*)&Ach[c][swz(16 + col0, kk*32 + krow*8)];
#pragma unroll
            for (int j = 0; j < 2; j++) {
                acc[c][0][j] = __builtin_amdgcn_mfma_f32_16x16x32_bf16(a0, B1[kk][j], acc[c][0][j], 0,0,0);
                acc[c][1][j] = __builtin_amdgcn_mfma_f32_16x16x32_bf16(a1, B1[kk][j], acc[c][1][j], 0,0,0);
            }
        }
    }
    // p -> Hch (C-space scalar writes), both tiles
#pragma unroll
    for (int c = 0; c < 2; c++)
#pragma unroll
        for (int m = 0; m < 2; m++)
#pragma unroll
            for (int j = 0; j < 2; j++)
#pragma unroll
                for (int ri = 0; ri < 4; ri++)
                    Hch[c][swz(m*16 + krow*4 + ri, wv*32 + j*16 + col0)] = (bf16_t)acc[c][m][j][ri];
    __syncthreads();

    // ---- h = relu(p + u + v), both tiles (row-space b128 RMW, fused in regs) ----
#pragma unroll
    for (int c = 0; c < 2; c++)
#pragma unroll
        for (int j = 0; j < 2; j++) {
            int r = wv * 8 + j * 4 + (lane >> 4);
            bf16x8 p8 = *(const bf16x8*)&Hch[c][swz(r, col0 * 8)];
            bf16x8 h8;
#pragma unroll
            for (int t = 0; t < 8; t++)
                h8[t] = (bf16_t)fmaxf((float)p8[t] + (float)uR[c][j][t] + (float)vR[c][j][t], 0.f);
            *(bf16x8*)&Hch[c][swz(r, col0 * 8)] = h8;
        }
    __syncthreads();

    // ---- A2 both tiles: out = h · W2 ----
#pragma unroll
    for (int c = 0; c < 2; c++)
#pragma unroll
        for (int m = 0; m < 2; m++)
#pragma unroll
            for (int j = 0; j < 2; j++) acc[c][m][j] = (f32x4){0,0,0,0};
#pragma unroll
    for (int kk = 0; kk < 4; kk++) {
#pragma unroll
        for (int c = 0; c < 2; c++) {
            bf16x8 a0 = *(const bf16x8*)&Hch[c][swz(     col0, kk*32 + krow*8)];
            bf16x8 a1 = *(const bf16x8*)&Hch[c][swz(16 + col0, kk*32 + krow*8)];
#pragma unroll
            for (int j = 0; j < 2; j++) {
                acc[c][0][j] = __builtin_amdgcn_mfma_f32_16x16x32_bf16(a0, B2[kk][j], acc[c][0][j], 0,0,0);
                acc[c][1][j] = __builtin_amdgcn_mfma_f32_16x16x32_bf16(a1, B2[kk][j], acc[c][1][j], 0,0,0);
            }
        }
    }
    // epilogue both tiles: out = relu(acc + b2)
#pragma unroll
    for (int c = 0; c < 2; c++)
#pragma unroll
        for (int m = 0; m < 2; m++)
#pragma unroll
            for (int j = 0; j < 2; j++)
#pragma unroll
                for (int ri = 0; ri < 4; ri++) {
                    int e = e0 + c * 32 + m*16 + krow*4 + ri;
                    if (e < E)
                        out[(long long)e * D + wv*32 + j*16 + col0] = fmaxf(acc[c][m][j][ri] + bias2[j], 0.f);
                }
}

extern "C" void kernel_launch(void* const* d_in, const int* in_sizes, int n_in,
                              void* d_out, int out_size, void* d_ws, size_t ws_size,
                              hipStream_t stream) {
    const float* x  = (const float*)d_in[0];
    const float* ea = (const float*)d_in[1];
    const int*   ei = (const int*)d_in[2];
    const float* W1 = (const float*)d_in[3];
    const float* b1 = (const float*)d_in[4];
    const float* W2 = (const float*)d_in[5];
    const float* b2 = (const float*)d_in[6];
    float* out = (float*)d_out;

    const int E = in_sizes[1] / D;      // 400000
    const int N = in_sizes[0] / D;      // 50000

    bf16_t* wsl = (bf16_t*)d_ws;                  // 128 KB: slice-major tiles (uv_kernel)
    bf16_t* wsf = wsl + 4 * 16384;                // 64 KB: fragment-packed W1c/W2 (edge)
    bf16_t* uu  = wsf + 32768;                    // N*128 bf16
    bf16_t* vv  = uu + (size_t)N * D;             // N*128 bf16

    prep_weights_kernel<<<272, 256, 0, stream>>>(W1, W2, wsl, wsf);

    hipFuncSetAttribute(reinterpret_cast<const void*>(uv_kernel),
                        hipFuncAttributeMaxDynamicSharedMemorySize, UV_LDS);
    uv_kernel<<<(N + 255) / 256, 512, UV_LDS, stream>>>(x, wsl, b1, uu, vv, N);

    int nblocks = (E + 63) / 64;                  // 6250
    edge_kernel<<<nblocks, 256, 0, stream>>>(uu, vv, ea, ei, wsf, b2, out, E);
}